// Round 5
// baseline (220.997 us; speedup 1.0000x reference)
//
#include <hip/hip_runtime.h>

#define B_    8
#define C_    1024
#define HID   64
#define N_    2048
#define RTOT  192

typedef __attribute__((ext_vector_type(8))) short   bf16x8;
typedef __attribute__((ext_vector_type(8))) unsigned short ush8;
typedef __attribute__((ext_vector_type(4))) unsigned short ush4;
typedef __attribute__((ext_vector_type(4))) float   f32x4;

// ---- workspace byte offsets ----
#define WSB_WBF   ((size_t)0)          // [192][1024]     bf16
#define WSB_TPG   ((size_t)393216)     // [B][192][2048]  bf16
#define WSB_THT   ((size_t)6684672)    // [B][2048][64]   bf16
#define WSB_M     ((size_t)8781824)    // [B][64][64]     f32
#define WSB_G     ((size_t)8912896)    // [B][64][64]     f32
#define WSB_S     ((size_t)9043968)    // [B][64]         f32 (contiguous after G)
#define WSB_WMBF  ((size_t)9046016)    // [B][1024][64]   bf16
#define WSB_SC    ((size_t)10094592)   // [1024] f32
#define WSB_SH    ((size_t)10098688)   // [1024] f32

static __device__ __forceinline__ unsigned short f2bf(float f) {
    union { float f; unsigned u; } v; v.f = f;
    unsigned r = v.u + 0x7fffu + ((v.u >> 16) & 1u);
    return (unsigned short)(r >> 16);
}
static __device__ __forceinline__ float bf2f(unsigned short h) {
    union { unsigned u; float f; } v; v.u = ((unsigned)h) << 16;
    return v.f;
}

// K0: weights -> bf16 (concat theta/phi/g)
__global__ __launch_bounds__(256) void wcvt(
    const float* __restrict__ tw, const float* __restrict__ pw,
    const float* __restrict__ gw, unsigned short* __restrict__ wbf)
{
    int idx = blockIdx.x * 256 + threadIdx.x;
    int r = idx >> 10, k = idx & 1023;
    float v = (r < 64) ? tw[(size_t)r * 1024 + k]
            : (r < 128) ? pw[(size_t)(r - 64) * 1024 + k]
                        : gw[(size_t)(r - 128) * 1024 + k];
    wbf[idx] = f2bf(v);
}

// K1: fused x-transpose + projection GEMM + theta-transpose output.
// Staging loads are batched 16-deep (register array + sched_barrier) to get
// MLP; without this the backend serializes loads 1-deep (R4: 41.6 us).
__global__ __launch_bounds__(256, 2) void proj_mfma(
    const float* __restrict__ x, const unsigned short* __restrict__ wbf,
    const float* __restrict__ tb, const float* __restrict__ pb,
    const float* __restrict__ gb, unsigned short* __restrict__ tpgbf,
    unsigned short* __restrict__ thT)
{
    const int b = blockIdx.y, n0 = blockIdx.x * 32;
    const int t = threadIdx.x, w = t >> 6, L = t & 63;
    const int lr = L & 15, q = L >> 4;
    __shared__ unsigned short A_lds[32][520];   // [n][k-half]; stride 1040B = 65x16B (b128-clean)

    const float* xb = x + (size_t)b * C_ * N_ + n0;
    const unsigned short* bp = wbf + ((size_t)(48 * w + lr)) * 1024 + q * 8;

    f32x4 acc[2][3] = {};

#pragma unroll
    for (int ph = 0; ph < 2; ph++) {
        if (ph) __syncthreads();   // protect LDS reuse
        // ---- stage k-half: ALL loads first (16-deep MLP), then cvt+write ----
        f32x4 regs[16];
#pragma unroll
        for (int i = 0; i < 8; i++) {
            int p = t + 256 * i;               // 0..2047
            int n4 = p & 7;                    // n-group of 4
            int c  = ((p >> 3) << 1);          // even c within half
            regs[2 * i]     = *(const f32x4*)(xb + (size_t)(512 * ph + c) * N_ + n4 * 4);
            regs[2 * i + 1] = *(const f32x4*)(xb + (size_t)(512 * ph + c + 1) * N_ + n4 * 4);
        }
        __builtin_amdgcn_sched_barrier(0);     // keep all 16 loads issued before consumers
#pragma unroll
        for (int i = 0; i < 8; i++) {
            int p = t + 256 * i;
            int n4 = p & 7;
            int c  = ((p >> 3) << 1);
            f32x4 v0 = regs[2 * i], v1 = regs[2 * i + 1];
#pragma unroll
            for (int r = 0; r < 4; r++) {
                unsigned val = (unsigned)f2bf(v0[r]) | ((unsigned)f2bf(v1[r]) << 16);
                *(unsigned*)&A_lds[n4 * 4 + r][c] = val;
            }
        }
        __syncthreads();
        // ---- barrier-free K-loop over this half ----
#pragma unroll
        for (int ks = 0; ks < 16; ks++) {
            const int kg = ph * 512 + ks * 32;
            bf16x8 B0 = *(const bf16x8*)(bp + kg);
            bf16x8 B1 = *(const bf16x8*)(bp + 16 * 1024 + kg);
            bf16x8 B2 = *(const bf16x8*)(bp + 32 * 1024 + kg);
            bf16x8 A0 = *(const bf16x8*)&A_lds[lr][ks * 32 + q * 8];
            bf16x8 A1 = *(const bf16x8*)&A_lds[16 + lr][ks * 32 + q * 8];
            acc[0][0] = __builtin_amdgcn_mfma_f32_16x16x32_bf16(A0, B0, acc[0][0], 0, 0, 0);
            acc[0][1] = __builtin_amdgcn_mfma_f32_16x16x32_bf16(A0, B1, acc[0][1], 0, 0, 0);
            acc[0][2] = __builtin_amdgcn_mfma_f32_16x16x32_bf16(A0, B2, acc[0][2], 0, 0, 0);
            acc[1][0] = __builtin_amdgcn_mfma_f32_16x16x32_bf16(A1, B0, acc[1][0], 0, 0, 0);
            acc[1][1] = __builtin_amdgcn_mfma_f32_16x16x32_bf16(A1, B1, acc[1][1], 0, 0, 0);
            acc[1][2] = __builtin_amdgcn_mfma_f32_16x16x32_bf16(A1, B2, acc[1][2], 0, 0, 0);
        }
    }

#pragma unroll
    for (int i = 0; i < 2; i++)
#pragma unroll
        for (int j = 0; j < 3; j++) {
            int rcol = 48 * w + 16 * j + lr;
            float bias = (rcol < 64) ? tb[rcol]
                       : (rcol < 128) ? pb[rcol - 64] : gb[rcol - 128];
            ush4 o;
#pragma unroll
            for (int rr = 0; rr < 4; rr++) o[rr] = f2bf(acc[i][j][rr] + bias);
            *(ush4*)(tpgbf + ((size_t)b * RTOT + rcol) * N_ + n0 + 16 * i + q * 4) = o;
            if (rcol < 64) {   // theta rows: also emit transposed copy for finalk
#pragma unroll
                for (int rr = 0; rr < 4; rr++)
                    thT[((size_t)b * N_ + n0 + 16 * i + q * 4 + rr) * HID + rcol] = o[rr];
            }
        }
}

// K2: gram products via MFMA, k-split (8 chunks) + atomics.
// p==0: M = phi·g^T ; p==1: G = theta·theta^T, plus S = theta·1
__global__ __launch_bounds__(256) void gram_mfma(
    const unsigned short* __restrict__ tpgbf, float* __restrict__ Mm,
    float* __restrict__ Gg, float* __restrict__ S)
{
    const int kc = blockIdx.x, p = blockIdx.y, b = blockIdx.z;
    const int t = threadIdx.x, w = t >> 6, L = t & 63;
    const int lr = L & 15, q = L >> 4;
    const unsigned short* base = tpgbf + (size_t)b * RTOT * N_;
    const unsigned short* Arow = base + (p ? 0 : (size_t)64 * N_);
    const unsigned short* Brow = base + (p ? 0 : (size_t)128 * N_);
    const unsigned short* ap = Arow + ((size_t)(16 * w + lr)) * N_ + kc * 256 + q * 8;
    const unsigned short* bp = Brow + ((size_t)lr) * N_ + kc * 256 + q * 8;

    bf16x8 ones;
#pragma unroll
    for (int j = 0; j < 8; j++) ones[j] = (short)0x3F80;

    f32x4 acc[4] = {};
    f32x4 accs = {};
#pragma unroll
    for (int it = 0; it < 8; ++it) {
        const int kn = it * 32;
        bf16x8 a = *(const bf16x8*)(ap + kn);
#pragma unroll
        for (int g = 0; g < 4; g++) {
            bf16x8 bb = *(const bf16x8*)(bp + (size_t)g * 16 * N_ + kn);
            acc[g] = __builtin_amdgcn_mfma_f32_16x16x32_bf16(a, bb, acc[g], 0, 0, 0);
        }
        if (p) accs = __builtin_amdgcn_mfma_f32_16x16x32_bf16(a, ones, accs, 0, 0, 0);
    }
    float* outp = (p ? Gg : Mm) + (size_t)b * HID * HID;
#pragma unroll
    for (int g = 0; g < 4; g++)
#pragma unroll
        for (int r = 0; r < 4; r++) {
            int row = 16 * w + q * 4 + r, col = 16 * g + lr;
            atomicAdd(outp + row * HID + col, acc[g][r]);
        }
    if (p && lr == 0) {
#pragma unroll
        for (int r = 0; r < 4; r++)
            atomicAdd(S + b * HID + 16 * w + q * 4 + r, accs[r]);
    }
}

// K3: fused wmk + statsk. One block per channel c, 64 lanes = e.
__global__ __launch_bounds__(64) void wmstat(
    const float* __restrict__ ww, const float* __restrict__ Mm,
    const float* __restrict__ S, const float* __restrict__ G,
    const float* __restrict__ wb, const float* __restrict__ gamma,
    const float* __restrict__ beta, unsigned short* __restrict__ wmbf,
    float* __restrict__ scale, float* __restrict__ shift2)
{
    const int c = blockIdx.x, lane = threadIdx.x;
    const float wbc = wb[c];
    const float* wr = ww + (size_t)c * HID;
    float asum = 0.f, asq = 0.f;
    for (int b = 0; b < B_; b++) {
        const float* mr = Mm + ((size_t)b * HID + lane) * HID;
        float acc = 0.f;
#pragma unroll
        for (int d = 0; d < HID; d += 4) {
            float4 m4 = *(const float4*)(mr + d);
            acc += wr[d] * m4.x + wr[d + 1] * m4.y + wr[d + 2] * m4.z + wr[d + 3] * m4.w;
        }
        unsigned short us = f2bf(acc * (1.0f / N_));
        wmbf[((size_t)b * C_ + c) * HID + lane] = us;
        float v = bf2f(us);
        float sv = S[b * HID + lane];
        float t1 = v * sv;
        for (int off = 32; off; off >>= 1) t1 += __shfl_down(t1, off);
        t1 = __shfl(t1, 0);
        const float* Gb = G + (size_t)b * HID * HID + (size_t)lane * HID;
        float inner = 0.f;
        for (int f = 0; f < HID; f++) inner = fmaf(Gb[f], __shfl(v, f), inner);
        float qq = v * inner;
        for (int off = 32; off; off >>= 1) qq += __shfl_down(qq, off);
        qq = __shfl(qq, 0);
        asum += t1;
        asq  += qq + 2.f * wbc * t1;
    }
    const float cnt = (float)B_ * (float)N_;
    const float inv = 1.0f / cnt;
    float mean = (asum + cnt * wbc) * inv;
    float e2   = (asq + cnt * wbc * wbc) * inv;
    float var  = e2 - mean * mean;
    float sc   = gamma[c] * rsqrtf(var + 1e-5f);
    if (lane == 0) {
        scale[c]  = sc;
        shift2[c] = beta[c] - mean * sc + sc * wbc;
    }
}

// K4: out = sc[c]*(Wm[b][c][:]·theta[:,n]) + sh[c] + x  (float4 stores along n)
__global__ __launch_bounds__(256) void finalk_mfma(
    const unsigned short* __restrict__ wmbf, const unsigned short* __restrict__ thT,
    const float* __restrict__ x, const float* __restrict__ scale,
    const float* __restrict__ shift2, float* __restrict__ out)
{
    const int b = blockIdx.z, c0 = blockIdx.y * 64, n0 = blockIdx.x * 64;
    const int t = threadIdx.x, w = t >> 6, L = t & 63;
    const int lr = L & 15, q = L >> 4;

    const unsigned short* ap = thT + ((size_t)b * N_ + n0 + 16 * w + lr) * HID + q * 8;
    const unsigned short* bp = wmbf + ((size_t)b * C_ + c0 + lr) * HID + q * 8;

    float4 xv[4];
    size_t xoff[4];
#pragma unroll
    for (int g = 0; g < 4; g++) {
        xoff[g] = ((size_t)b * C_ + c0 + 16 * g + lr) * N_ + n0 + 16 * w + q * 4;
        xv[g] = *(const float4*)(x + xoff[g]);
    }

    bf16x8 A0 = *(const bf16x8*)(ap);
    bf16x8 A1 = *(const bf16x8*)(ap + 32);
    f32x4 acc[4] = {};
#pragma unroll
    for (int g = 0; g < 4; g++) {
        bf16x8 Bg0 = *(const bf16x8*)(bp + (size_t)g * 16 * HID);
        bf16x8 Bg1 = *(const bf16x8*)(bp + (size_t)g * 16 * HID + 32);
        acc[g] = __builtin_amdgcn_mfma_f32_16x16x32_bf16(A0, Bg0, acc[g], 0, 0, 0);
        acc[g] = __builtin_amdgcn_mfma_f32_16x16x32_bf16(A1, Bg1, acc[g], 0, 0, 0);
    }
#pragma unroll
    for (int g = 0; g < 4; g++) {
        int c = c0 + 16 * g + lr;
        float sc = scale[c], sh = shift2[c];
        float4 o;
        o.x = fmaf(sc, acc[g][0], sh) + xv[g].x;
        o.y = fmaf(sc, acc[g][1], sh) + xv[g].y;
        o.z = fmaf(sc, acc[g][2], sh) + xv[g].z;
        o.w = fmaf(sc, acc[g][3], sh) + xv[g].w;
        *(float4*)(out + xoff[g]) = o;
    }
}

extern "C" void kernel_launch(void* const* d_in, const int* in_sizes, int n_in,
                              void* d_out, int out_size, void* d_ws, size_t ws_size,
                              hipStream_t stream)
{
    const float* x  = (const float*)d_in[0];
    const float* tw = (const float*)d_in[1];
    const float* tb = (const float*)d_in[2];
    const float* pw = (const float*)d_in[3];
    const float* pb = (const float*)d_in[4];
    const float* gw = (const float*)d_in[5];
    const float* gb = (const float*)d_in[6];
    const float* ww = (const float*)d_in[7];
    const float* wb = (const float*)d_in[8];
    const float* gamma = (const float*)d_in[9];
    const float* beta  = (const float*)d_in[10];
    float* out = (float*)d_out;

    char* ws = (char*)d_ws;
    unsigned short* wbf   = (unsigned short*)(ws + WSB_WBF);
    unsigned short* tpgbf = (unsigned short*)(ws + WSB_TPG);
    unsigned short* thT   = (unsigned short*)(ws + WSB_THT);
    float* Mm   = (float*)(ws + WSB_M);
    float* Gg   = (float*)(ws + WSB_G);
    float* S    = (float*)(ws + WSB_S);
    unsigned short* wmbf = (unsigned short*)(ws + WSB_WMBF);
    float* scl  = (float*)(ws + WSB_SC);
    float* shf  = (float*)(ws + WSB_SH);

    // zero M, G, S (contiguous)
    hipMemsetAsync(Mm, 0, (size_t)(2 * B_ * HID * HID + B_ * HID) * sizeof(float), stream);

    wcvt<<<dim3(RTOT * 1024 / 256), 256, 0, stream>>>(tw, pw, gw, wbf);
    proj_mfma<<<dim3(64, B_), 256, 0, stream>>>(x, wbf, tb, pb, gb, tpgbf, thT);
    gram_mfma<<<dim3(8, 2, B_), 256, 0, stream>>>(tpgbf, Mm, Gg, S);
    wmstat<<<C_, 64, 0, stream>>>(ww, Mm, S, Gg, wb, gamma, beta, wmbf, scl, shf);
    finalk_mfma<<<dim3(32, 16, B_), 256, 0, stream>>>(wmbf, thT, x, scl, shf, out);
}